// Round 5
// baseline (552.913 us; speedup 1.0000x reference)
//
#include <hip/hip_runtime.h>
#include <hip/hip_fp16.h>

// Pipeline (all fp16 MFMA, f32 accum), 2-phase double-buffered GEMMs:
//   cvt Wq,Wk,Wv ; cvt e -> slot1 ; k=e@Wk^T+bk -> slot2
//   cvt b -> slot1 (e dead) ; q=b@Wq^T+bq -> slot3 ; v=b@Wv^T+bv -> slot4 [BT,608]
//   attn=tanh(q@k^T) -> slot1 (b dead), batched z=64, pad cols zeroed
//   out=attn@v^T -> f32 d_out, batched, K=608 (pads zero)
// All GEMMs NT: C[i,j] = sum_k A[i,k]*Bt[j,k], both row-major, K contiguous.
//
// LDS layout is FRAGMENT-MAJOR (conflict-free, rule #21 compliant):
//   global_load_lds writes linearly (chunk ch -> LDS offset ch*16B); we permute
//   the per-lane GLOBAL source instead: chunk ch -> mb=ch>>6, kg=(ch>>4)&3,
//   r=ch&15 -> global (row m0+mb*16+r, col kg*8). A wave's MFMA fragment read
//   (frag mi) is then chunks (w*4+mi)*64 + lane: 64 consecutive 16B chunks ->
//   ds_read_b128 with zero bank conflicts (was 8-way at [128][32] linear).
// Batched GEMMs use batch->XCD co-location (batch working set L2-resident).

typedef _Float16 f16x8 __attribute__((ext_vector_type(8)));
typedef float f32x4 __attribute__((ext_vector_type(4)));

__global__ void cvt8_kernel(const float* __restrict__ src, _Float16* __restrict__ dst,
                            long long n8) {
    long long i = blockIdx.x * (long long)blockDim.x + threadIdx.x;
    const long long stride = gridDim.x * (long long)blockDim.x;
    for (; i < n8; i += stride) {
        const float4 f0 = ((const float4*)src)[2 * i];
        const float4 f1 = ((const float4*)src)[2 * i + 1];
        f16x8 h;
        h[0] = (_Float16)f0.x; h[1] = (_Float16)f0.y; h[2] = (_Float16)f0.z; h[3] = (_Float16)f0.w;
        h[4] = (_Float16)f1.x; h[5] = (_Float16)f1.y; h[6] = (_Float16)f1.z; h[7] = (_Float16)f1.w;
        ((f16x8*)dst)[i] = h;
    }
}

__device__ __forceinline__ void gload16(const _Float16* g, _Float16* l) {
    __builtin_amdgcn_global_load_lds(
        (const __attribute__((address_space(1))) unsigned int*)(g),
        (__attribute__((address_space(3))) unsigned int*)(l),
        16, 0, 0);
}

// 128x128 tile, 4 waves (2x2 of 64x64), BK=32, MFMA 16x16x32 f16.
// C/D: col = lane&15, row = (lane>>4)*4 + r   [guide §3, m89/m91-verified]
// MODE 0: 1D grid over tiles, bijective XCD chunking (m204), z=0.
// MODE 1: batched; grid = 8*nTiles*(B/8); bid -> (xcd, z, tile) co-location.
template<bool TANH, bool OUT_F16, bool BIAS, int MODE>
__global__ __launch_bounds__(256)
void gemm_nt_f16(const _Float16* __restrict__ A, const _Float16* __restrict__ Bt,
                 const float* __restrict__ bias, void* __restrict__ Cp,
                 int M, int Nreal, int Nstore, int K,
                 int lda, int ldb, int ldc, int nTileN, int nTiles,
                 long long sA, long long sB, long long sC)
{
    __shared__ __align__(16) _Float16 lds[4 * 128 * 32];   // A0 B0 A1 B1 (32 KB)
    _Float16* As0 = lds;
    _Float16* Bs0 = lds + 4096;
    _Float16* As1 = lds + 8192;
    _Float16* Bs1 = lds + 12288;

    int bid = blockIdx.x;
    int z, tm, tn;
    if (MODE == 0) {
        const int nwg = gridDim.x;
        const int q8 = nwg >> 3, r8 = nwg & 7;
        const int xcd = bid & 7, loc = bid >> 3;
        bid = (xcd < r8 ? xcd * (q8 + 1) : r8 * (q8 + 1) + (xcd - r8) * q8) + loc;
        z = 0;
        tm = bid / nTileN; tn = bid - tm * nTileN;
    } else {
        const int xcd = bid & 7, idx = bid >> 3;
        const int g = idx / nTiles, tile = idx - g * nTiles;
        z = g * 8 + xcd;                      // batch z: all its tiles on one XCD
        tm = tile / nTileN; tn = tile - tm * nTileN;
    }
    const int m0 = tm << 7, n0 = tn << 7;

    const _Float16* Az = A + (size_t)z * sA;
    const _Float16* Bz = Bt + (size_t)z * sB;

    const int tid = threadIdx.x;
    const int lane = tid & 63;
    const int wid = tid >> 6;
    const int wm = wid >> 1, wn = wid & 1;

    // staging source decode for this thread's two chunks (ch, ch+256):
    // chunk ch -> mb=ch>>6, kg=(ch>>4)&3, r=ch&15 ; row mb*16+r, col kg*8
    const int kgc = ((tid >> 4) & 3) << 3;           // same kg for both chunks
    const int rl0 = (tid >> 6) * 16 + (tid & 15);    // tile row of chunk tid
    const int rl1 = rl0 + 64;                        // tile row of chunk tid+256
    const int rA0 = (m0 + rl0 < M ? m0 + rl0 : M - 1);
    const int rA1 = (m0 + rl1 < M ? m0 + rl1 : M - 1);
    const int rB0 = (n0 + rl0 < Nreal ? n0 + rl0 : Nreal - 1);
    const int rB1 = (n0 + rl1 < Nreal ? n0 + rl1 : Nreal - 1);
    const _Float16* pA0 = Az + (size_t)rA0 * lda + kgc;
    const _Float16* pA1 = Az + (size_t)rA1 * lda + kgc;
    const _Float16* pB0 = Bz + (size_t)rB0 * ldb + kgc;
    const _Float16* pB1 = Bz + (size_t)rB1 * ldb + kgc;

    const int o0 = tid * 8, o1 = (tid + 256) * 8;

    // fragment LDS read offsets (halfwords): chunk (w*4+mi)*64 + lane, *8
    const int fAo = (wm * 4 * 64 + lane) * 8;        // + mi*512
    const int fBo = (wn * 4 * 64 + lane) * 8;        // + ni*512

    const f32x4 z4 = {0.f, 0.f, 0.f, 0.f};
    f32x4 acc[4][4];
#pragma unroll
    for (int i = 0; i < 4; ++i)
#pragma unroll
        for (int j = 0; j < 4; ++j) acc[i][j] = z4;

    // prologue: stage tile 0
    gload16(pA0, As0 + o0); gload16(pA1, As0 + o1);
    gload16(pB0, Bs0 + o0); gload16(pB1, Bs0 + o1);
    __syncthreads();                       // vmcnt(0) drain: tile 0 ready

    _Float16 *cA = As0, *cB = Bs0, *nA = As1, *nB = Bs1;
    for (int k0 = 0; k0 < K; k0 += 32) {
        const int k1 = k0 + 32;
        if (k1 < K) {                      // prefetch next tile into alt buffer
            gload16(pA0 + k1, nA + o0); gload16(pA1 + k1, nA + o1);
            gload16(pB0 + k1, nB + o0); gload16(pB1 + k1, nB + o1);
        }
        f16x8 a[4], b[4];
#pragma unroll
        for (int mi = 0; mi < 4; ++mi) a[mi] = *(const f16x8*)(cA + fAo + mi * 512);
#pragma unroll
        for (int ni = 0; ni < 4; ++ni) b[ni] = *(const f16x8*)(cB + fBo + ni * 512);
#pragma unroll
        for (int mi = 0; mi < 4; ++mi)
#pragma unroll
            for (int ni = 0; ni < 4; ++ni)
                acc[mi][ni] = __builtin_amdgcn_mfma_f32_16x16x32_f16(a[mi], b[ni], acc[mi][ni], 0, 0, 0);
        __syncthreads();                   // drains prefetch vmcnt + guards overwrite
        _Float16* t;
        t = cA; cA = nA; nA = t;
        t = cB; cB = nB; nB = t;
    }

    // epilogue: bias -> tanh -> store (zero padded cols [Nreal, Nstore))
    const int cr0 = (lane >> 4) << 2;
    const int cc = lane & 15;
    float*    Cf = (float*)Cp    + (size_t)z * sC;
    _Float16* Ch = (_Float16*)Cp + (size_t)z * sC;
#pragma unroll
    for (int mi = 0; mi < 4; ++mi) {
#pragma unroll
        for (int ni = 0; ni < 4; ++ni) {
            const int gc = n0 + wn * 64 + ni * 16 + cc;
            if (gc >= Nstore) continue;
            const bool real = gc < Nreal;
            float bb = 0.f;
            if (BIAS) bb = real ? bias[gc] : 0.f;
#pragma unroll
            for (int r = 0; r < 4; ++r) {
                const int gr = m0 + wm * 64 + mi * 16 + cr0 + r;
                if (gr >= M) continue;
                float x = real ? (acc[mi][ni][r] + bb) : 0.f;
                if (TANH) x = tanhf(x);
                if (OUT_F16) Ch[(size_t)gr * ldc + gc] = (_Float16)x;
                else         Cf[(size_t)gr * ldc + gc] = x;
            }
        }
    }
}

extern "C" void kernel_launch(void* const* d_in, const int* in_sizes, int n_in,
                              void* d_out, int out_size, void* d_ws, size_t ws_size,
                              hipStream_t stream)
{
    const float* b  = (const float*)d_in[0];
    const float* e  = (const float*)d_in[1];
    const float* Wq = (const float*)d_in[2];
    const float* bq = (const float*)d_in[3];
    const float* Wk = (const float*)d_in[4];
    const float* bk = (const float*)d_in[5];
    const float* Wv = (const float*)d_in[6];
    const float* bv = (const float*)d_in[7];
    float* out = (float*)d_out;

    const int BT = 36928, D = 768, T = 577, S = 577, Sp = 608;

    // ws layout (halfwords): weights + 3x BT*768 slots + 1x BT*608 = ~218 MB
    _Float16* Wq_h  = (_Float16*)d_ws;
    _Float16* Wk_h  = Wq_h + 589824;
    _Float16* Wv_h  = Wk_h + 589824;
    _Float16* slot1 = Wv_h + 443136;                 // e_h -> b_h -> at_h
    _Float16* slot2 = slot1 + (size_t)BT * D;        // k_h
    _Float16* slot3 = slot2 + (size_t)BT * D;        // q_h
    _Float16* slot4 = slot3 + (size_t)BT * D;        // v_h [BT,608]

    cvt8_kernel<<<288, 256, 0, stream>>>(Wq, Wq_h, 73728);
    cvt8_kernel<<<288, 256, 0, stream>>>(Wk, Wk_h, 73728);
    cvt8_kernel<<<217, 256, 0, stream>>>(Wv, Wv_h, 55392);

    // e -> fp16
    cvt8_kernel<<<2048, 256, 0, stream>>>(e, slot1, 3545088);
    // k = e@Wk^T + bk   [BT,768]
    gemm_nt_f16<false, true, true, 0><<<dim3(1734, 1, 1), 256, 0, stream>>>(
        slot1, Wk_h, bk, slot2, BT, D, D, D, D, D, D, 6, 0, 0, 0, 0);
    // b -> fp16 (e_h dead)
    cvt8_kernel<<<2048, 256, 0, stream>>>(b, slot1, 3545088);
    // q = b@Wq^T + bq   [BT,768]
    gemm_nt_f16<false, true, true, 0><<<dim3(1734, 1, 1), 256, 0, stream>>>(
        slot1, Wq_h, bq, slot3, BT, D, D, D, D, D, D, 6, 0, 0, 0, 0);
    // v = b@Wv^T + bv   [BT,608] (cols 577..607 zeroed)
    gemm_nt_f16<false, true, true, 0><<<dim3(1445, 1, 1), 256, 0, stream>>>(
        slot1, Wv_h, bv, slot4, BT, S, Sp, D, D, D, Sp, 5, 0, 0, 0, 0);
    // attn = tanh(q@k^T) -> slot1 (b_h dead)  batched [64][577,608]
    gemm_nt_f16<true, true, false, 1><<<dim3(1600, 1, 1), 256, 0, stream>>>(
        slot3, slot2, nullptr, slot1, T, S, Sp, D, D, D, Sp, 5, 25,
        (long long)T * D, (long long)T * D, (long long)T * Sp);
    // out = attn@v^T   batched [64][577,577] f32, K=608 (pads zero)
    gemm_nt_f16<false, false, false, 1><<<dim3(1600, 1, 1), 256, 0, stream>>>(
        slot1, slot4, nullptr, out, T, T, T, Sp, Sp, Sp, T, 5, 25,
        (long long)T * Sp, (long long)T * Sp, (long long)T * T);
}

// Round 6
// 454.737 us; speedup vs baseline: 1.2159x; 1.2159x over previous
//
#include <hip/hip_runtime.h>
#include <hip/hip_fp16.h>

// Pipeline (all fp16 MFMA, f32 accum), 2-phase double-buffered GEMMs:
//   cvt Wq,Wk,Wv ; cvt e -> slot1 ; k=e@Wk^T+bk -> slot2
//   cvt b -> slot1 (e dead) ; q=b@Wq^T+bq -> slot3 ; v=b@Wv^T+bv -> slot4 [BT,608]
//   attn=tanh(q@k^T) -> slot1 (b dead), batched z=64, pad cols zeroed
//   out=attn@v^T -> f32 d_out, batched, K=608 (pads zero)
// All GEMMs NT: C[i,j] = sum_k A[i,k]*Bt[j,k], both row-major, K contiguous.
//
// LDS layout: row-major 16B chunks (slot s -> row s>>2) with XOR-swizzled
// k-slot: slot s holds global cols ((s&3) ^ ((s>>3)&3))*8 .. +7 of row s>>2.
//  - write side (global_load_lds is lane-linear in LDS): thread t sources
//    row t>>2, col ((t&3)^((t>>3)&3))*8 -> each 4-lane group = one 64B line
//    (intra-line permutation only; coalescing identical to linear layout).
//  - read side: fragment lane l (row R, k-half h=l>>4) reads slot
//    R*4 + (h ^ ((R>>1)&3)); slot residues mod 8 cover all 8 banks-groups
//    exactly 2x per 16 lanes -> 2-way = free (m136). Rule #21: same involution
//    on both sides.
// Batched GEMMs use batch->XCD co-location (batch working set L2-resident).

typedef _Float16 f16x8 __attribute__((ext_vector_type(8)));
typedef float f32x4 __attribute__((ext_vector_type(4)));

__global__ void cvt8_kernel(const float* __restrict__ src, _Float16* __restrict__ dst,
                            long long n8) {
    long long i = blockIdx.x * (long long)blockDim.x + threadIdx.x;
    const long long stride = gridDim.x * (long long)blockDim.x;
    for (; i < n8; i += stride) {
        const float4 f0 = ((const float4*)src)[2 * i];
        const float4 f1 = ((const float4*)src)[2 * i + 1];
        f16x8 h;
        h[0] = (_Float16)f0.x; h[1] = (_Float16)f0.y; h[2] = (_Float16)f0.z; h[3] = (_Float16)f0.w;
        h[4] = (_Float16)f1.x; h[5] = (_Float16)f1.y; h[6] = (_Float16)f1.z; h[7] = (_Float16)f1.w;
        ((f16x8*)dst)[i] = h;
    }
}

__device__ __forceinline__ void gload16(const _Float16* g, _Float16* l) {
    __builtin_amdgcn_global_load_lds(
        (const __attribute__((address_space(1))) unsigned int*)(g),
        (__attribute__((address_space(3))) unsigned int*)(l),
        16, 0, 0);
}

// 128x128 tile, 4 waves (2x2 of 64x64), BK=32, MFMA 16x16x32 f16.
// C/D: col = lane&15, row = (lane>>4)*4 + r   [guide §3, m89/m91-verified]
// MODE 0: 1D grid over tiles, bijective XCD chunking (m204), z=0.
// MODE 1: batched; grid = 8*nTiles*(B/8); bid -> (xcd, z, tile) co-location.
template<bool TANH, bool OUT_F16, bool BIAS, int MODE>
__global__ __launch_bounds__(256)
void gemm_nt_f16(const _Float16* __restrict__ A, const _Float16* __restrict__ Bt,
                 const float* __restrict__ bias, void* __restrict__ Cp,
                 int M, int Nreal, int Nstore, int K,
                 int lda, int ldb, int ldc, int nTileN, int nTiles,
                 long long sA, long long sB, long long sC)
{
    __shared__ __align__(16) _Float16 lds[4 * 128 * 32];   // A0 B0 A1 B1 (32 KB)
    _Float16* As0 = lds;
    _Float16* Bs0 = lds + 4096;
    _Float16* As1 = lds + 8192;
    _Float16* Bs1 = lds + 12288;

    int bid = blockIdx.x;
    int z, tm, tn;
    if (MODE == 0) {
        const int nwg = gridDim.x;
        const int q8 = nwg >> 3, r8 = nwg & 7;
        const int xcd = bid & 7, loc = bid >> 3;
        bid = (xcd < r8 ? xcd * (q8 + 1) : r8 * (q8 + 1) + (xcd - r8) * q8) + loc;
        z = 0;
        tm = bid / nTileN; tn = bid - tm * nTileN;
    } else {
        const int xcd = bid & 7, idx = bid >> 3;
        const int g = idx / nTiles, tile = idx - g * nTiles;
        z = g * 8 + xcd;                      // batch z: all its tiles on one XCD
        tm = tile / nTileN; tn = tile - tm * nTileN;
    }
    const int m0 = tm << 7, n0 = tn << 7;

    const _Float16* Az = A + (size_t)z * sA;
    const _Float16* Bz = Bt + (size_t)z * sB;

    const int tid = threadIdx.x;
    const int lane = tid & 63;
    const int wid = tid >> 6;
    const int wm = wid >> 1, wn = wid & 1;

    // staging: thread t owns slots t and t+256. slot s -> row s>>2,
    // col ((s&3)^((s>>3)&3))*8. (s=t and t+256 share the same XOR term and
    // the same col since (t+256)>>3 differs by 32, &3 equal.)
    const int r0 = tid >> 2;                                  // rows 0..63; +64
    const int c0 = (((tid & 3) ^ ((tid >> 3) & 3)) << 3);     // swizzled col
    const int rA0 = (m0 + r0      < M ? m0 + r0      : M - 1);
    const int rA1 = (m0 + r0 + 64 < M ? m0 + r0 + 64 : M - 1);
    const int rB0 = (n0 + r0      < Nreal ? n0 + r0      : Nreal - 1);
    const int rB1 = (n0 + r0 + 64 < Nreal ? n0 + r0 + 64 : Nreal - 1);
    const _Float16* pA0 = Az + (size_t)rA0 * lda + c0;
    const _Float16* pA1 = Az + (size_t)rA1 * lda + c0;
    const _Float16* pB0 = Bz + (size_t)rB0 * ldb + c0;
    const _Float16* pB1 = Bz + (size_t)rB1 * ldb + c0;

    const int o0 = tid * 8, o1 = (tid + 256) * 8;

    // fragment LDS read offsets (halfwords): lane l, row R = w*64 + mi*16 + rr,
    // k-half h = l>>4 -> slot R*4 + (h ^ ((rr>>1)&3))  (upper row bits are
    // multiples of 8 so (R>>1)&3 == (rr>>1)&3). +mi*512 per fragment.
    const int rr = lane & 15;
    const int hh = lane >> 4;
    const int sw = (rr >> 1) & 3;
    const int fAo = ((wm * 64 + rr) * 4 + (hh ^ sw)) * 8;    // + mi*512
    const int fBo = ((wn * 64 + rr) * 4 + (hh ^ sw)) * 8;    // + ni*512

    const f32x4 z4 = {0.f, 0.f, 0.f, 0.f};
    f32x4 acc[4][4];
#pragma unroll
    for (int i = 0; i < 4; ++i)
#pragma unroll
        for (int j = 0; j < 4; ++j) acc[i][j] = z4;

    // prologue: stage tile 0
    gload16(pA0, As0 + o0); gload16(pA1, As0 + o1);
    gload16(pB0, Bs0 + o0); gload16(pB1, Bs0 + o1);
    __syncthreads();                       // vmcnt(0) drain: tile 0 ready

    _Float16 *cA = As0, *cB = Bs0, *nA = As1, *nB = Bs1;
    for (int k0 = 0; k0 < K; k0 += 32) {
        const int k1 = k0 + 32;
        if (k1 < K) {                      // prefetch next tile into alt buffer
            gload16(pA0 + k1, nA + o0); gload16(pA1 + k1, nA + o1);
            gload16(pB0 + k1, nB + o0); gload16(pB1 + k1, nB + o1);
        }
        f16x8 a[4], b[4];
#pragma unroll
        for (int mi = 0; mi < 4; ++mi) a[mi] = *(const f16x8*)(cA + fAo + mi * 512);
#pragma unroll
        for (int ni = 0; ni < 4; ++ni) b[ni] = *(const f16x8*)(cB + fBo + ni * 512);
#pragma unroll
        for (int mi = 0; mi < 4; ++mi)
#pragma unroll
            for (int ni = 0; ni < 4; ++ni)
                acc[mi][ni] = __builtin_amdgcn_mfma_f32_16x16x32_f16(a[mi], b[ni], acc[mi][ni], 0, 0, 0);
        __syncthreads();                   // drains prefetch vmcnt + guards overwrite
        _Float16* t;
        t = cA; cA = nA; nA = t;
        t = cB; cB = nB; nB = t;
    }

    // epilogue: bias -> tanh -> store (zero padded cols [Nreal, Nstore))
    const int cr0 = (lane >> 4) << 2;
    const int cc = lane & 15;
    float*    Cf = (float*)Cp    + (size_t)z * sC;
    _Float16* Ch = (_Float16*)Cp + (size_t)z * sC;
#pragma unroll
    for (int mi = 0; mi < 4; ++mi) {
#pragma unroll
        for (int ni = 0; ni < 4; ++ni) {
            const int gc = n0 + wn * 64 + ni * 16 + cc;
            if (gc >= Nstore) continue;
            const bool real = gc < Nreal;
            float bb = 0.f;
            if (BIAS) bb = real ? bias[gc] : 0.f;
#pragma unroll
            for (int r = 0; r < 4; ++r) {
                const int gr = m0 + wm * 64 + mi * 16 + cr0 + r;
                if (gr >= M) continue;
                float x = real ? (acc[mi][ni][r] + bb) : 0.f;
                if (TANH) x = tanhf(x);
                if (OUT_F16) Ch[(size_t)gr * ldc + gc] = (_Float16)x;
                else         Cf[(size_t)gr * ldc + gc] = x;
            }
        }
    }
}

extern "C" void kernel_launch(void* const* d_in, const int* in_sizes, int n_in,
                              void* d_out, int out_size, void* d_ws, size_t ws_size,
                              hipStream_t stream)
{
    const float* b  = (const float*)d_in[0];
    const float* e  = (const float*)d_in[1];
    const float* Wq = (const float*)d_in[2];
    const float* bq = (const float*)d_in[3];
    const float* Wk = (const float*)d_in[4];
    const float* bk = (const float*)d_in[5];
    const float* Wv = (const float*)d_in[6];
    const float* bv = (const float*)d_in[7];
    float* out = (float*)d_out;

    const int BT = 36928, D = 768, T = 577, S = 577, Sp = 608;

    // ws layout (halfwords): weights + 3x BT*768 slots + 1x BT*608 = ~218 MB
    _Float16* Wq_h  = (_Float16*)d_ws;
    _Float16* Wk_h  = Wq_h + 589824;
    _Float16* Wv_h  = Wk_h + 589824;
    _Float16* slot1 = Wv_h + 443136;                 // e_h -> b_h -> at_h
    _Float16* slot2 = slot1 + (size_t)BT * D;        // k_h
    _Float16* slot3 = slot2 + (size_t)BT * D;        // q_h
    _Float16* slot4 = slot3 + (size_t)BT * D;        // v_h [BT,608]

    cvt8_kernel<<<288, 256, 0, stream>>>(Wq, Wq_h, 73728);
    cvt8_kernel<<<288, 256, 0, stream>>>(Wk, Wk_h, 73728);
    cvt8_kernel<<<217, 256, 0, stream>>>(Wv, Wv_h, 55392);

    // e -> fp16
    cvt8_kernel<<<2048, 256, 0, stream>>>(e, slot1, 3545088);
    // k = e@Wk^T + bk   [BT,768]
    gemm_nt_f16<false, true, true, 0><<<dim3(1734, 1, 1), 256, 0, stream>>>(
        slot1, Wk_h, bk, slot2, BT, D, D, D, D, D, D, 6, 0, 0, 0, 0);
    // b -> fp16 (e_h dead)
    cvt8_kernel<<<2048, 256, 0, stream>>>(b, slot1, 3545088);
    // q = b@Wq^T + bq   [BT,768]
    gemm_nt_f16<false, true, true, 0><<<dim3(1734, 1, 1), 256, 0, stream>>>(
        slot1, Wq_h, bq, slot3, BT, D, D, D, D, D, D, 6, 0, 0, 0, 0);
    // v = b@Wv^T + bv   [BT,608] (cols 577..607 zeroed)
    gemm_nt_f16<false, true, true, 0><<<dim3(1445, 1, 1), 256, 0, stream>>>(
        slot1, Wv_h, bv, slot4, BT, S, Sp, D, D, D, Sp, 5, 0, 0, 0, 0);
    // attn = tanh(q@k^T) -> slot1 (b_h dead)  batched [64][577,608]
    gemm_nt_f16<true, true, false, 1><<<dim3(1600, 1, 1), 256, 0, stream>>>(
        slot3, slot2, nullptr, slot1, T, S, Sp, D, D, D, Sp, 5, 25,
        (long long)T * D, (long long)T * D, (long long)T * Sp);
    // out = attn@v^T   batched [64][577,577] f32, K=608 (pads zero)
    gemm_nt_f16<false, false, false, 1><<<dim3(1600, 1, 1), 256, 0, stream>>>(
        slot1, slot4, nullptr, out, T, T, T, Sp, Sp, Sp, T, 5, 25,
        (long long)T * Sp, (long long)T * Sp, (long long)T * T);
}

// Round 7
// 427.472 us; speedup vs baseline: 1.2934x; 1.0638x over previous
//
#include <hip/hip_runtime.h>
#include <hip/hip_fp16.h>

// Pipeline (all fp16 MFMA, f32 accum), 3-stage pipelined GEMMs (counted vmcnt):
//   cvt Wq,Wk,Wv ; cvt e -> slot1 ; k=e@Wk^T+bk -> slot2
//   cvt b -> slot1 (e dead) ; q=b@Wq^T+bq -> slot3 ; v=b@Wv^T+bv -> slot4 [BT,608]
//   attn=tanh(q@k^T) -> slot1 (b dead), batched z=64, pad cols zeroed
//   out=attn@v^T -> f32 d_out, batched, K=608 (pads zero)
// All GEMMs NT: C[i,j] = sum_k A[i,k]*Bt[j,k], both row-major, K contiguous.
//
// LDS: 3 stages x (A 8KB + B 8KB) = 48 KB. Row-major 16B chunks with
// XOR-swizzled k-slot (R6 layout: 0 bank conflicts, coalesced writes):
//   slot s -> row s>>2, global cols ((s&3)^((s>>3)&3))*8 .. +7.
//   read: lane l row R, k-half h reads slot R*4 + (h ^ ((R>>1)&3)).
// K-loop (T4, guide 5.5): per step j: s_waitcnt vmcnt(4) [tile j's 4 loads,
// issued 2 iters ago] -> s_barrier -> sched_barrier(0) -> issue stage(j+2)
// -> 16 MFMA on tile j. Never vmcnt(0) in the main loop (last iter peeled).
// Overwrite safety: all waves past barrier have consumed tile j-1 (MFMA
// operand waits force ds_read completion before issue) -- m201 argument.
// Batched GEMMs use batch->XCD co-location (batch working set L2-resident).

typedef _Float16 f16x8 __attribute__((ext_vector_type(8)));
typedef float f32x4 __attribute__((ext_vector_type(4)));

__global__ void cvt8_kernel(const float* __restrict__ src, _Float16* __restrict__ dst,
                            long long n8) {
    long long i = blockIdx.x * (long long)blockDim.x + threadIdx.x;
    const long long stride = gridDim.x * (long long)blockDim.x;
    for (; i < n8; i += stride) {
        const float4 f0 = ((const float4*)src)[2 * i];
        const float4 f1 = ((const float4*)src)[2 * i + 1];
        f16x8 h;
        h[0] = (_Float16)f0.x; h[1] = (_Float16)f0.y; h[2] = (_Float16)f0.z; h[3] = (_Float16)f0.w;
        h[4] = (_Float16)f1.x; h[5] = (_Float16)f1.y; h[6] = (_Float16)f1.z; h[7] = (_Float16)f1.w;
        ((f16x8*)dst)[i] = h;
    }
}

__device__ __forceinline__ void gload16(const _Float16* g, _Float16* l) {
    __builtin_amdgcn_global_load_lds(
        (const __attribute__((address_space(1))) unsigned int*)(g),
        (__attribute__((address_space(3))) unsigned int*)(l),
        16, 0, 0);
}

// 128x128 tile, 4 waves (2x2 of 64x64), BK=32, MFMA 16x16x32 f16.
// C/D: col = lane&15, row = (lane>>4)*4 + r   [guide §3, m89/m91-verified]
// MODE 0: 1D grid over tiles, bijective XCD chunking (m204), z=0.
// MODE 1: batched; grid = 8*nTiles*(B/8); bid -> (xcd, z, tile) co-location.
template<bool TANH, bool OUT_F16, bool BIAS, int MODE>
__global__ __launch_bounds__(256)
void gemm_nt_f16(const _Float16* __restrict__ A, const _Float16* __restrict__ Bt,
                 const float* __restrict__ bias, void* __restrict__ Cp,
                 int M, int Nreal, int Nstore, int K,
                 int lda, int ldb, int ldc, int nTileN, int nTiles,
                 long long sA, long long sB, long long sC)
{
    __shared__ __align__(16) _Float16 lds[3 * 8192];   // 3 x (A 4096 + B 4096) hw

    int bid = blockIdx.x;
    int z, tm, tn;
    if (MODE == 0) {
        const int nwg = gridDim.x;
        const int q8 = nwg >> 3, r8 = nwg & 7;
        const int xcd = bid & 7, loc = bid >> 3;
        bid = (xcd < r8 ? xcd * (q8 + 1) : r8 * (q8 + 1) + (xcd - r8) * q8) + loc;
        z = 0;
        tm = bid / nTileN; tn = bid - tm * nTileN;
    } else {
        const int xcd = bid & 7, idx = bid >> 3;
        const int g = idx / nTiles, tile = idx - g * nTiles;
        z = g * 8 + xcd;                      // batch z: all its tiles on one XCD
        tm = tile / nTileN; tn = tile - tm * nTileN;
    }
    const int m0 = tm << 7, n0 = tn << 7;

    const _Float16* Az = A + (size_t)z * sA;
    const _Float16* Bz = Bt + (size_t)z * sB;

    const int tid = threadIdx.x;
    const int lane = tid & 63;
    const int wid = tid >> 6;
    const int wm = wid >> 1, wn = wid & 1;

    // staging: thread t owns slots t and t+256. slot s -> row s>>2,
    // col ((s&3)^((s>>3)&3))*8  (both slots share the same XOR term).
    const int r0 = tid >> 2;
    const int c0 = (((tid & 3) ^ ((tid >> 3) & 3)) << 3);
    const int rA0 = (m0 + r0      < M ? m0 + r0      : M - 1);
    const int rA1 = (m0 + r0 + 64 < M ? m0 + r0 + 64 : M - 1);
    const int rB0 = (n0 + r0      < Nreal ? n0 + r0      : Nreal - 1);
    const int rB1 = (n0 + r0 + 64 < Nreal ? n0 + r0 + 64 : Nreal - 1);
    const _Float16* pA0 = Az + (size_t)rA0 * lda + c0;
    const _Float16* pA1 = Az + (size_t)rA1 * lda + c0;
    const _Float16* pB0 = Bz + (size_t)rB0 * ldb + c0;
    const _Float16* pB1 = Bz + (size_t)rB1 * ldb + c0;

    const int o0 = tid * 8, o1 = (tid + 256) * 8;

    // fragment LDS read offsets (halfwords): row R = w*64+mi*16+rr, half h:
    // slot R*4 + (h ^ ((rr>>1)&3)); + mi*512 per fragment.
    const int rr = lane & 15;
    const int hh = lane >> 4;
    const int sw = (rr >> 1) & 3;
    const int fAo = ((wm * 64 + rr) * 4 + (hh ^ sw)) * 8;
    const int fBo = ((wn * 64 + rr) * 4 + (hh ^ sw)) * 8;

    const f32x4 z4 = {0.f, 0.f, 0.f, 0.f};
    f32x4 acc[4][4];
#pragma unroll
    for (int i = 0; i < 4; ++i)
#pragma unroll
        for (int j = 0; j < 4; ++j) acc[i][j] = z4;

    const int nt = K >> 5;                 // K-steps (>= 19 in this pipeline)

#define STAGE(si, kt)                                              \
    do {                                                           \
        _Float16* base_ = lds + (si) * 8192;                       \
        const int ko_ = (kt) << 5;                                 \
        gload16(pA0 + ko_, base_ + o0);                            \
        gload16(pA1 + ko_, base_ + o1);                            \
        gload16(pB0 + ko_, base_ + 4096 + o0);                     \
        gload16(pB1 + ko_, base_ + 4096 + o1);                     \
    } while (0)

#define COMPUTE(si)                                                            \
    do {                                                                       \
        const _Float16* cA_ = lds + (si) * 8192;                               \
        const _Float16* cB_ = cA_ + 4096;                                      \
        f16x8 a_[4], b_[4];                                                    \
        _Pragma("unroll")                                                      \
        for (int mi = 0; mi < 4; ++mi) a_[mi] = *(const f16x8*)(cA_ + fAo + mi * 512); \
        _Pragma("unroll")                                                      \
        for (int ni = 0; ni < 4; ++ni) b_[ni] = *(const f16x8*)(cB_ + fBo + ni * 512); \
        _Pragma("unroll")                                                      \
        for (int mi = 0; mi < 4; ++mi)                                         \
            _Pragma("unroll")                                                  \
            for (int ni = 0; ni < 4; ++ni)                                     \
                acc[mi][ni] = __builtin_amdgcn_mfma_f32_16x16x32_f16(          \
                    a_[mi], b_[ni], acc[mi][ni], 0, 0, 0);                     \
    } while (0)

    // prologue: 2 tiles in flight
    STAGE(0, 0);
    STAGE(1, 1);

    for (int j = 0; j < nt - 1; ++j) {
        asm volatile("s_waitcnt vmcnt(4)" ::: "memory");   // tile j's loads done
        __builtin_amdgcn_s_barrier();
        __builtin_amdgcn_sched_barrier(0);
        if (j + 2 < nt) STAGE((j + 2) % 3, j + 2);
        COMPUTE(j % 3);
    }
    // peeled last step: only tile nt-1's loads remain
    asm volatile("s_waitcnt vmcnt(0)" ::: "memory");
    __builtin_amdgcn_s_barrier();
    __builtin_amdgcn_sched_barrier(0);
    COMPUTE((nt - 1) % 3);

#undef STAGE
#undef COMPUTE

    // epilogue: bias -> tanh -> store (zero padded cols [Nreal, Nstore))
    const int cr0 = (lane >> 4) << 2;
    const int cc = lane & 15;
    float*    Cf = (float*)Cp    + (size_t)z * sC;
    _Float16* Ch = (_Float16*)Cp + (size_t)z * sC;
#pragma unroll
    for (int mi = 0; mi < 4; ++mi) {
#pragma unroll
        for (int ni = 0; ni < 4; ++ni) {
            const int gc = n0 + wn * 64 + ni * 16 + cc;
            if (gc >= Nstore) continue;
            const bool real = gc < Nreal;
            float bb = 0.f;
            if (BIAS) bb = real ? bias[gc] : 0.f;
#pragma unroll
            for (int r = 0; r < 4; ++r) {
                const int gr = m0 + wm * 64 + mi * 16 + cr0 + r;
                if (gr >= M) continue;
                float x = real ? (acc[mi][ni][r] + bb) : 0.f;
                if (TANH) x = tanhf(x);
                if (OUT_F16) Ch[(size_t)gr * ldc + gc] = (_Float16)x;
                else         Cf[(size_t)gr * ldc + gc] = x;
            }
        }
    }
}

extern "C" void kernel_launch(void* const* d_in, const int* in_sizes, int n_in,
                              void* d_out, int out_size, void* d_ws, size_t ws_size,
                              hipStream_t stream)
{
    const float* b  = (const float*)d_in[0];
    const float* e  = (const float*)d_in[1];
    const float* Wq = (const float*)d_in[2];
    const float* bq = (const float*)d_in[3];
    const float* Wk = (const float*)d_in[4];
    const float* bk = (const float*)d_in[5];
    const float* Wv = (const float*)d_in[6];
    const float* bv = (const float*)d_in[7];
    float* out = (float*)d_out;

    const int BT = 36928, D = 768, T = 577, S = 577, Sp = 608;

    // ws layout (halfwords): weights + 3x BT*768 slots + 1x BT*608 = ~218 MB
    _Float16* Wq_h  = (_Float16*)d_ws;
    _Float16* Wk_h  = Wq_h + 589824;
    _Float16* Wv_h  = Wk_h + 589824;
    _Float16* slot1 = Wv_h + 443136;                 // e_h -> b_h -> at_h
    _Float16* slot2 = slot1 + (size_t)BT * D;        // k_h
    _Float16* slot3 = slot2 + (size_t)BT * D;        // q_h
    _Float16* slot4 = slot3 + (size_t)BT * D;        // v_h [BT,608]

    cvt8_kernel<<<288, 256, 0, stream>>>(Wq, Wq_h, 73728);
    cvt8_kernel<<<288, 256, 0, stream>>>(Wk, Wk_h, 73728);
    cvt8_kernel<<<217, 256, 0, stream>>>(Wv, Wv_h, 55392);

    // e -> fp16
    cvt8_kernel<<<2048, 256, 0, stream>>>(e, slot1, 3545088);
    // k = e@Wk^T + bk   [BT,768]
    gemm_nt_f16<false, true, true, 0><<<dim3(1734, 1, 1), 256, 0, stream>>>(
        slot1, Wk_h, bk, slot2, BT, D, D, D, D, D, D, 6, 0, 0, 0, 0);
    // b -> fp16 (e_h dead)
    cvt8_kernel<<<2048, 256, 0, stream>>>(b, slot1, 3545088);
    // q = b@Wq^T + bq   [BT,768]
    gemm_nt_f16<false, true, true, 0><<<dim3(1734, 1, 1), 256, 0, stream>>>(
        slot1, Wq_h, bq, slot3, BT, D, D, D, D, D, D, 6, 0, 0, 0, 0);
    // v = b@Wv^T + bv   [BT,608] (cols 577..607 zeroed)
    gemm_nt_f16<false, true, true, 0><<<dim3(1445, 1, 1), 256, 0, stream>>>(
        slot1, Wv_h, bv, slot4, BT, S, Sp, D, D, D, Sp, 5, 0, 0, 0, 0);
    // attn = tanh(q@k^T) -> slot1 (b_h dead)  batched [64][577,608]
    gemm_nt_f16<true, true, false, 1><<<dim3(1600, 1, 1), 256, 0, stream>>>(
        slot3, slot2, nullptr, slot1, T, S, Sp, D, D, D, Sp, 5, 25,
        (long long)T * D, (long long)T * D, (long long)T * Sp);
    // out = attn@v^T   batched [64][577,577] f32, K=608 (pads zero)
    gemm_nt_f16<false, false, false, 1><<<dim3(1600, 1, 1), 256, 0, stream>>>(
        slot1, slot4, nullptr, out, T, T, T, Sp, Sp, Sp, T, 5, 25,
        (long long)T * Sp, (long long)T * Sp, (long long)T * T);
}